// Round 10
// baseline (746.070 us; speedup 1.0000x reference)
//
#include <hip/hip_runtime.h>
#include <hip/hip_bf16.h>
#include <stdint.h>

// Problem dims (fixed by reference)
#define Bq    8192
#define Hh    8
#define Dd    16
#define Kk    16
#define Nn    4096
#define DFf   16
#define ROWS  (Bq*Hh)          // 65536
#define COLS  (Dd*Kk)          // 256
#define EPSF  1e-6f

typedef unsigned long long u64;
typedef unsigned int u32;
typedef __attribute__((ext_vector_type(8)))  short bf16x8;
typedef __attribute__((ext_vector_type(16))) float f32x16;

// async global->LDS, 16B per lane; LDS dest = wave-uniform base + lane*16
#define GLOAD_LDS(g, l) __builtin_amdgcn_global_load_lds( \
    (const __attribute__((address_space(1))) u32*)(g), \
    (__attribute__((address_space(3))) u32*)(l), 16, 0, 0)

// ---------- helpers ----------
__device__ __forceinline__ float dot4(float4 a, float4 b) {
    return fmaf(a.x, b.x, fmaf(a.y, b.y, fmaf(a.z, b.z, a.w * b.w)));
}
__device__ __forceinline__ float wave_sum(float v) {
    #pragma unroll
    for (int m = 32; m > 0; m >>= 1) v += __shfl_xor(v, m, 64);
    return v;
}
__device__ __forceinline__ u32 f32_sortable(float f) {
    u32 u = __float_as_uint(f);
    return (u & 0x80000000u) ? ~u : (u | 0x80000000u);
}
// pack 2 floats -> 2 bf16 (RNE); low 16 bits = a
__device__ __forceinline__ u32 pk2(float a, float b) {
    union { __hip_bfloat162 h; u32 u; } v;
    v.h = __float22bfloat162_rn(make_float2(a, b));
    return v.u;
}
// exact fp32 rerank, R2's accepted expression tree (sequential fmaf over 64 float4s)
__device__ __forceinline__ void exact_rerank(const float* __restrict__ X,
                                             const float* __restrict__ CB,
                                             const float* __restrict__ xx,
                                             const float* __restrict__ cbn,
                                             int row, int col,
                                             u64* __restrict__ best) {
    const float4* xp = (const float4*)(X + (size_t)row * COLS);
    const float4* cp = (const float4*)(CB + (size_t)col * COLS);
    float d = 0.f;
    #pragma unroll 8
    for (int q = 0; q < 64; ++q) {
        float4 a = xp[q], b = cp[q];
        d = fmaf(a.x, b.x, d); d = fmaf(a.y, b.y, d);
        d = fmaf(a.z, b.z, d); d = fmaf(a.w, b.w, d);
    }
    float d2e = fmaf(-2.f, d, xx[row]) + cbn[col];
    u64 pk = ((u64)f32_sortable(d2e) << 32) | (u32)col;
    atomicMin(&best[row], pk);
}

// ---------- kernel 0: xx[r], X->bf16 (row-major), init best/cbn_max ----------
__global__ __launch_bounds__(256) void k_prep(const float* __restrict__ X,
                                              short* __restrict__ Xh,
                                              float* __restrict__ xx,
                                              u64* __restrict__ best,
                                              u32* __restrict__ cbn_max) {
    int r    = blockIdx.x * 4 + (threadIdx.x >> 6);
    int lane = threadIdx.x & 63;
    float4 v = *reinterpret_cast<const float4*>(X + (size_t)r * COLS + lane * 4);
    uint2 p; p.x = pk2(v.x, v.y); p.y = pk2(v.z, v.w);
    *reinterpret_cast<uint2*>(Xh + (size_t)r * COLS + lane * 4) = p;
    float s = wave_sum(v.x*v.x + v.y*v.y + v.z*v.z + v.w*v.w);
    if (lane == 0) { xx[r] = s; best[r] = ~0ull; }
    if (blockIdx.x == 0 && threadIdx.x == 0) *cbn_max = 0u;
}

// ---------- kernel 1: codebook fp32 + 32x32-FRAGMENT-ORDER bf16 + |cb|^2 ----------
// CBf layout, per 32-code tile (16 KB): frag f = kstep (0..15) is 1 KB:
// lane l = h*32 + c holds B[col = tile*32 + c][k = kstep*16 + h*8 .. +8].
// Screen stages a tile linearly via global_load_lds and ds_read_b128's it
// conflict-free (lane*16B consecutive).
__global__ __launch_bounds__(256) void k_codebook(const float* __restrict__ fc,
                                                  const float* __restrict__ Wi,
                                                  const float* __restrict__ Wo,
                                                  float* __restrict__ CB,
                                                  short* __restrict__ CBf,
                                                  float* __restrict__ cbn,
                                                  u32* __restrict__ cbn_max) {
    int n = blockIdx.x, tid = threadIdx.x;
    int o = tid >> 4, k = tid & 15;
    __shared__ float fcs[256], wis[256], wos[256], hs[256], sq[256];
    __shared__ short cvs_sh[256];
    fcs[tid] = fc[(size_t)n * 256 + tid];
    wis[tid] = Wi[tid];
    wos[tid] = Wo[tid];
    __syncthreads();
    float hp = 0.f;
    #pragma unroll
    for (int i = 0; i < 16; ++i) hp = fmaf(wis[o*16 + i], fcs[i*16 + k], hp);
    hs[tid] = hp;
    __syncthreads();
    float h0 = hs[o * 16];
    float x3 = h0 * h0 * h0;
    float inner = 0.7978845608028654f * fmaf(0.044715f, x3, h0);
    float g = 0.5f * h0 * (1.f + tanhf(inner));
    float hg = hp * g;
    __syncthreads();
    hs[tid] = hg;
    __syncthreads();
    float cv = 0.f;
    #pragma unroll
    for (int i = 0; i < 16; ++i) cv = fmaf(wos[o*16 + i], hs[i*16 + k], cv);
    CB[(size_t)n * 256 + tid] = cv;
    { union { __hip_bfloat16 h; short s; } c; c.h = __float2bfloat16(cv);
      cvs_sh[tid] = c.s; }
    sq[tid] = cv * cv;
    __syncthreads();
    #pragma unroll
    for (int st = 128; st > 0; st >>= 1) {
        if (tid < st) sq[tid] += sq[tid + st];
        __syncthreads();
    }
    if (tid == 0) { cbn[n] = sq[0]; atomicMax(cbn_max, __float_as_uint(sq[0])); }
    // swizzled write: 32 chunks of 8 bf16 -> 32x32-fragment slots
    if (tid < 32) {
        int kc = tid;                      // 8-short chunk, k = kc*8
        int tile = n >> 5, c = n & 31;
        int kstep = kc >> 1, h = kc & 1;
        size_t off = (size_t)tile * 8192 + kstep * 512 + h * 256 + c * 8;
        *reinterpret_cast<uint4*>(CBf + off) =
            *reinterpret_cast<const uint4*>(&cvs_sh[kc * 8]);
    }
}

// ---------- kernel 2: 32x32x16-MFMA screen, LDS triple-buffer, counted vmcnt ----------
// 512 blocks x 256 threads (4 waves x 32 rows = 128 rows/block); all 4096
// codes streamed once as 128 tiles of 32 codes (16 KB each, fragment-ordered)
// through a TRIPLE LDS buffer. Per tile (R7's proven discipline):
//   s_waitcnt vmcnt(8) -> tile t landed (t+1,t+2 in flight, 4 issues/thread ea)
//   s_barrier (A); 16x ds_read_b128 + 16x mfma_32x32x16 (~8x more work per
//   barrier than R7 -> overhead amortized); epilogue in g-form (g = -2 dot +
//   cbn; per-row xx cancels in argmin): per-reg cross-lane min over the 32
//   col-lanes, running rmin[16], collect vs thr = rmin + delta_wave (safe:
//   rmin includes current tile -> true argmin + exact ties always enter);
//   s_barrier (B); STAGE tile t+3 into freed buffer (vmcnt never 0).
// A-frags af[16] (64 VGPR) held across all tiles. C/D layout per m74:
// col=lane&31, row=(reg&3)+8*(reg>>2)+4*(lane>>5). Candidates -> 8 LDS slots
// per tid, exact fp32 rerank after the loop; overflow reranks inline (adds
// vmem into the vmcnt FIFO but only AHEAD of future stage groups -> counted
// waits still conservative-correct).
__global__ __launch_bounds__(256, 2) void k_screen_fused(
        const short* __restrict__ Xh,
        const short* __restrict__ CBf,
        const float* __restrict__ X,
        const float* __restrict__ CB,
        const float* __restrict__ cbn,
        const float* __restrict__ xx,
        u64* __restrict__ best,
        const u32* __restrict__ cbn_max) {
    __shared__ __align__(16) short Bs[3][8192];   // 3 x 16 KB
    __shared__ float cbn_s[Nn];                   // 16 KB
    __shared__ u32 cand_lds[8][256];              // 8 KB

    const int tid  = threadIdx.x;
    const int lane = tid & 63;
    const int w    = tid >> 6;           // wave 0..3
    const int cl   = lane & 31;          // col-lane
    const int kh   = lane >> 5;          // k-half
    const int bmBase = blockIdx.x * 128; // 32 rows per wave

#define STAGE(t_, buf) do { \
        int _t = (t_); \
        _Pragma("unroll") \
        for (int _i = 0; _i < 4; ++_i) { \
            int _f = _i * 4 + w; \
            const short* _g = CBf + (size_t)_t * 8192 + _f * 512 + lane * 8; \
            GLOAD_LDS(_g, &Bs[(buf)][_f * 512]); \
        } \
    } while (0)

    // cbn -> LDS (all 4096 codes)
    #pragma unroll
    for (int j = 0; j < 4; ++j)
        *reinterpret_cast<float4*>(&cbn_s[tid * 16 + j * 4]) =
            *reinterpret_cast<const float4*>(&cbn[tid * 16 + j * 4]);

    // A fragments: af[kstep], lane holds row bmBase+w*32+cl, k = kstep*16+kh*8
    bf16x8 af[16];
    {
        const short* ap = Xh + ((size_t)(bmBase + w * 32 + cl) << 8) + kh * 8;
        #pragma unroll
        for (int ks = 0; ks < 16; ++ks)
            af[ks] = *reinterpret_cast<const bf16x8*>(ap + ks * 16);
    }

    // per-wave delta (max over the wave's 32 rows; xx spread ~5% -> safe+cheap)
    float dw;
    {
        float xr = xx[bmBase + w * 32 + cl];
        float dl = fmaf(0.003f, sqrtf(xr * __uint_as_float(*cbn_max)), 0.01f);
        #pragma unroll
        for (int m = 1; m <= 32; m <<= 1) dl = fmaxf(dl, __shfl_xor(dl, m, 64));
        dw = dl;
    }

    float rmin[16];
    #pragma unroll
    for (int r = 0; r < 16; ++r) rmin[r] = 1e30f;

    __syncthreads();            // full drain (prologue only): vmcnt back to 0

    STAGE(0, 0); STAGE(1, 1); STAGE(2, 2);   // 12 issues/thread outstanding

    int ccnt = 0;
    int p = 0;

    for (int t = 0; t < 128; ++t) {
        asm volatile("s_waitcnt vmcnt(8)" ::: "memory");
        __builtin_amdgcn_sched_barrier(0);
        __builtin_amdgcn_s_barrier();               // (A) buf[p] ready
        __builtin_amdgcn_sched_barrier(0);

        f32x16 acc;
        #pragma unroll
        for (int r = 0; r < 16; ++r) acc[r] = 0.f;

        const short* Bt = &Bs[p][0];
        #pragma unroll
        for (int ks = 0; ks < 16; ++ks) {
            bf16x8 bv = *reinterpret_cast<const bf16x8*>(&Bt[ks * 512 + lane * 8]);
            acc = __builtin_amdgcn_mfma_f32_32x32x16_bf16(af[ks], bv, acc, 0, 0, 0);
        }

        // epilogue: g = -2*dot + cbn[col]; per-reg row = m74 mapping
        float cbnv = cbn_s[t * 32 + cl];
        #pragma unroll
        for (int r = 0; r < 16; ++r) {
            float g = fmaf(-2.f, acc[r], cbnv);
            float m = g;
            #pragma unroll
            for (int d = 1; d <= 16; d <<= 1)     // min over the 32 col-lanes
                m = fminf(m, __shfl_xor(m, d, 64));
            rmin[r] = fminf(rmin[r], m);          // running min incl. this tile
            if (g <= rmin[r] + dw) {
                u32 enc = ((u32)r << 12) | (u32)(t * 32 + cl);
                if (ccnt < 8) cand_lds[ccnt][tid] = enc;
                else exact_rerank(X, CB, xx, cbn,   // ~never: adds strictness only
                        bmBase + w * 32 + (r & 3) + 8 * (r >> 2) + 4 * kh,
                        t * 32 + cl, best);
                ++ccnt;
            }
        }

        __builtin_amdgcn_sched_barrier(0);
        __builtin_amdgcn_s_barrier();               // (B) buf[p] free
        __builtin_amdgcn_sched_barrier(0);
        STAGE((t + 3) & 127, p);    // wrap keeps vmcnt count uniform
        p = (p == 2) ? 0 : p + 1;
    }

    // post-loop: exact fp32 rerank of buffered candidates (R2's tree)
    int nc = ccnt < 8 ? ccnt : 8;
    for (int i = 0; i < nc; ++i) {
        u32 e = cand_lds[i][tid];
        int r = (int)(e >> 12);
        int row = bmBase + w * 32 + (r & 3) + 8 * (r >> 2) + 4 * kh;
        exact_rerank(X, CB, xx, cbn, row, (int)(e & 0xFFF), best);
    }
#undef STAGE
}

// ---------- kernel 3: gather e, Householder STE ----------
__global__ __launch_bounds__(256) void k_epilogue(const float* __restrict__ X,
                                                  const float* __restrict__ CB,
                                                  const u64* __restrict__ best,
                                                  float* __restrict__ Eout,
                                                  float* __restrict__ Sout) {
    int r    = blockIdx.x * 4 + (threadIdx.x >> 6);
    int lane = threadIdx.x & 63;
    int idx  = (int)(best[r] & 0xffffffffull);

    float4 xv = *reinterpret_cast<const float4*>(X  + (size_t)r   * COLS + lane * 4);
    float4 ev = *reinterpret_cast<const float4*>(CB + (size_t)idx * COLS + lane * 4);

    float xn2 = wave_sum(dot4(xv, xv));
    float en2 = wave_sum(dot4(ev, ev));
    float xn = sqrtf(xn2), en = sqrtf(en2);
    float invx = 1.f / fmaxf(xn, EPSF);
    float inve = 1.f / fmaxf(en, EPSF);

    float4 xd, ed, sd0;
    xd.x = xv.x*invx; xd.y = xv.y*invx; xd.z = xv.z*invx; xd.w = xv.w*invx;
    ed.x = ev.x*inve; ed.y = ev.y*inve; ed.z = ev.z*inve; ed.w = ev.w*inve;
    sd0.x = xd.x+ed.x; sd0.y = xd.y+ed.y; sd0.z = xd.z+ed.z; sd0.w = xd.w+ed.w;

    float sdn2 = wave_sum(dot4(sd0, sd0));
    float p1   = wave_sum(dot4(sd0, xv));
    float p2   = wave_sum(dot4(xd,  xv));
    float invs = 1.f / fmaxf(sqrtf(sdn2), EPSF);

    float csd = -2.f * invs * invs * p1;
    float ced =  2.f * p2;
    float4 rr;
    rr.x = fmaf(csd, sd0.x, fmaf(ced, ed.x, xv.x));
    rr.y = fmaf(csd, sd0.y, fmaf(ced, ed.y, xv.y));
    rr.z = fmaf(csd, sd0.z, fmaf(ced, ed.z, xv.z));
    rr.w = fmaf(csd, sd0.w, fmaf(ced, ed.w, xv.w));
    float sc = en * invx;
    float4 sv; sv.x = rr.x*sc; sv.y = rr.y*sc; sv.z = rr.z*sc; sv.w = rr.w*sc;

    *reinterpret_cast<float4*>(Eout + (size_t)r * COLS + lane * 4) = ev;
    *reinterpret_cast<float4*>(Sout + (size_t)r * COLS + lane * 4) = sv;
}

// ---------- launcher ----------
extern "C" void kernel_launch(void* const* d_in, const int* in_sizes, int n_in,
                              void* d_out, int out_size, void* d_ws, size_t ws_size,
                              hipStream_t stream) {
    const float* x  = (const float*)d_in[0];
    const float* fc = (const float*)d_in[1];
    const float* Wi = (const float*)d_in[2];
    const float* Wo = (const float*)d_in[3];

    // ws layout (~5 MB)
    char* ws = (char*)d_ws;
    u64*   best    = (u64*)ws;                            ws += (size_t)ROWS * 8;
    float* CBws    = (float*)ws;                          ws += (size_t)Nn * COLS * 4;
    float* cbn     = (float*)ws;                          ws += (size_t)Nn * 4;
    float* xx      = (float*)ws;                          ws += (size_t)ROWS * 4;
    u32*   cbn_max = (u32*)ws;

    // bf16 copies live in d_out (128 MiB), only overwritten by k_epilogue at
    // the very end: Xh = 32 MiB at offset 0, CBf = 2 MiB at offset 64 MiB.
    short* Xh  = (short*)d_out;
    short* CBf = (short*)((char*)d_out + (64u << 20));

    float* Eout = (float*)d_out;
    float* Sout = Eout + (size_t)ROWS * COLS;

    k_prep<<<ROWS / 4, 256, 0, stream>>>(x, Xh, xx, best, cbn_max);
    k_codebook<<<Nn, 256, 0, stream>>>(fc, Wi, Wo, CBws, CBf, cbn, cbn_max);
    k_screen_fused<<<ROWS / 128, 256, 0, stream>>>(Xh, CBf, x, CBws, cbn, xx, best, cbn_max);
    k_epilogue<<<ROWS / 4, 256, 0, stream>>>(x, CBws, best, Eout, Sout);
}

// Round 11
// 580.091 us; speedup vs baseline: 1.2861x; 1.2861x over previous
//
#include <hip/hip_runtime.h>
#include <hip/hip_bf16.h>
#include <stdint.h>

// Problem dims (fixed by reference)
#define Bq    8192
#define Hh    8
#define Dd    16
#define Kk    16
#define Nn    4096
#define DFf   16
#define ROWS  (Bq*Hh)          // 65536
#define COLS  (Dd*Kk)          // 256
#define EPSF  1e-6f

typedef unsigned long long u64;
typedef unsigned int u32;
typedef __attribute__((ext_vector_type(8))) short bf16x8;
typedef __attribute__((ext_vector_type(4))) float f32x4;

// ---------- helpers ----------
__device__ __forceinline__ float dot4(float4 a, float4 b) {
    return fmaf(a.x, b.x, fmaf(a.y, b.y, fmaf(a.z, b.z, a.w * b.w)));
}
__device__ __forceinline__ float wave_sum(float v) {
    #pragma unroll
    for (int m = 32; m > 0; m >>= 1) v += __shfl_xor(v, m, 64);
    return v;
}
__device__ __forceinline__ u32 f32_sortable(float f) {
    u32 u = __float_as_uint(f);
    return (u & 0x80000000u) ? ~u : (u | 0x80000000u);
}
// pack 2 floats -> 2 bf16 (RNE); low 16 bits = a
__device__ __forceinline__ u32 pk2(float a, float b) {
    union { __hip_bfloat162 h; u32 u; } v;
    v.h = __float22bfloat162_rn(make_float2(a, b));
    return v.u;
}
// exact fp32 rerank, R2's accepted expression tree (sequential fmaf over 64 float4s)
__device__ __forceinline__ void exact_rerank(const float* __restrict__ X,
                                             const float* __restrict__ CB,
                                             const float* __restrict__ xx,
                                             const float* __restrict__ cbn,
                                             int row, int col,
                                             u64* __restrict__ best) {
    const float4* xp = (const float4*)(X + (size_t)row * COLS);
    const float4* cp = (const float4*)(CB + (size_t)col * COLS);
    float d = 0.f;
    #pragma unroll 8
    for (int q = 0; q < 64; ++q) {
        float4 a = xp[q], b = cp[q];
        d = fmaf(a.x, b.x, d); d = fmaf(a.y, b.y, d);
        d = fmaf(a.z, b.z, d); d = fmaf(a.w, b.w, d);
    }
    float d2e = fmaf(-2.f, d, xx[row]) + cbn[col];
    u64 pk = ((u64)f32_sortable(d2e) << 32) | (u32)col;
    atomicMin(&best[row], pk);
}

// ---------- kernel 0: xx[r], X->bf16 (linear), init best/cbn_max ----------
__global__ __launch_bounds__(256) void k_prep(const float* __restrict__ X,
                                              short* __restrict__ Xh,
                                              float* __restrict__ xx,
                                              u64* __restrict__ best,
                                              u32* __restrict__ cbn_max) {
    int r    = blockIdx.x * 4 + (threadIdx.x >> 6);
    int lane = threadIdx.x & 63;
    float4 v = *reinterpret_cast<const float4*>(X + (size_t)r * COLS + lane * 4);
    uint2 p; p.x = pk2(v.x, v.y); p.y = pk2(v.z, v.w);
    *reinterpret_cast<uint2*>(Xh + (size_t)r * COLS + lane * 4) = p;
    float s = wave_sum(v.x*v.x + v.y*v.y + v.z*v.z + v.w*v.w);
    if (lane == 0) { xx[r] = s; best[r] = ~0ull; }
    if (blockIdx.x == 0 && threadIdx.x == 0) *cbn_max = 0u;
}

// ---------- kernel 1: codebook fp32 + FRAGMENT-ORDER bf16 + |cb|^2 ----------
// CBf layout (R8, verified): fragment f = bn*64 + kb*16 + ks*8 + ni holds
// 64 lanes x 8 bf16: lane l = k_hi*16 + (code&15), data = code row
// (bn*128+ni*16+(code&15)), k = kb*64 + (ks*4 + k_hi)*8 .. +8. One coalesced
// global_load_dwordx4 per fragment in the screen.
__global__ __launch_bounds__(256) void k_codebook(const float* __restrict__ fc,
                                                  const float* __restrict__ Wi,
                                                  const float* __restrict__ Wo,
                                                  float* __restrict__ CB,
                                                  short* __restrict__ CBf,
                                                  float* __restrict__ cbn,
                                                  u32* __restrict__ cbn_max) {
    int n = blockIdx.x, tid = threadIdx.x;
    int o = tid >> 4, k = tid & 15;
    __shared__ float fcs[256], wis[256], wos[256], hs[256], sq[256];
    __shared__ short cvs_sh[256];
    fcs[tid] = fc[(size_t)n * 256 + tid];
    wis[tid] = Wi[tid];
    wos[tid] = Wo[tid];
    __syncthreads();
    float hp = 0.f;
    #pragma unroll
    for (int i = 0; i < 16; ++i) hp = fmaf(wis[o*16 + i], fcs[i*16 + k], hp);
    hs[tid] = hp;
    __syncthreads();
    float h0 = hs[o * 16];
    float x3 = h0 * h0 * h0;
    float inner = 0.7978845608028654f * fmaf(0.044715f, x3, h0);
    float g = 0.5f * h0 * (1.f + tanhf(inner));
    float hg = hp * g;
    __syncthreads();
    hs[tid] = hg;
    __syncthreads();
    float cv = 0.f;
    #pragma unroll
    for (int i = 0; i < 16; ++i) cv = fmaf(wos[o*16 + i], hs[i*16 + k], cv);
    CB[(size_t)n * 256 + tid] = cv;
    { union { __hip_bfloat16 h; short s; } c; c.h = __float2bfloat16(cv);
      cvs_sh[tid] = c.s; }
    sq[tid] = cv * cv;
    __syncthreads();
    #pragma unroll
    for (int st = 128; st > 0; st >>= 1) {
        if (tid < st) sq[tid] += sq[tid + st];
        __syncthreads();
    }
    if (tid == 0) { cbn[n] = sq[0]; atomicMax(cbn_max, __float_as_uint(sq[0])); }
    // swizzled write: 32 chunks of 8 bf16 -> fragment slots
    if (tid < 32) {
        int kc = tid;                          // global 8-short chunk 0..31
        int bn = n >> 7, ni = (n >> 4) & 7, rl = n & 15;
        int kb = kc >> 3, kgl = kc & 7, ks = kgl >> 2, khi = kgl & 3;
        int lane = khi * 16 + rl;
        size_t off = ((size_t)(bn * 64 + kb * 16 + ks * 8 + ni) * 64 + lane) * 8;
        *reinterpret_cast<uint4*>(CBf + off) =
            *reinterpret_cast<const uint4*>(&cvs_sh[kc * 8]);
    }
}

// ---------- kernel 2: register-direct screen, CODE-SPLIT grid for occupancy ----------
// 1024 blocks x 256 threads: bm = bid>>1 (128-row band), half = bid&1 (2048
// codes). Wave w owns 32 rows (mi=2 x 16); A in regs (af[2][8]); B fragments
// via coalesced global_load_dwordx4 from fragment-ordered CBf (L1/L2-hot).
// Barrier-free, self-paced waves. LDS only 16 KB (half-cbn 8K + cand 8K) ->
// 4 blocks/CU, 16 waves/CU (2x R8's latency coverage; R8 was grid-limited
// at 2 blocks/CU). Per-(mi,rg) epilogue: running row-min over THIS BLOCK's
// partial code range + candidate collect vs thr = rmin + delta. Partial-sweep
// safety: for any col c with d2_exact(c) = global min, d2a(c) <= d2_min_exact
// + err <= rmin_partial + 2*err <= rmin_partial + delta -> the true argmin
// and all exact ties enter some block's candidate set; exact fp32 rerank +
// global packed atomicMin(best) merges blocks. Candidates -> LDS [8][256];
// rerank after the loop; overflow reranks inline (adds strictness only).
__global__ __launch_bounds__(256, 2) void k_screen_fused(
        const short* __restrict__ Xh,
        const short* __restrict__ CBf,
        const float* __restrict__ X,
        const float* __restrict__ CB,
        const float* __restrict__ cbn,
        const float* __restrict__ xx,
        u64* __restrict__ best,
        const u32* __restrict__ cbn_max) {
    __shared__ float cbn_s[2048];        // 8 KB: this block's code half
    __shared__ u32 cand_lds[8][256];     // 8 KB, [slot][tid]

    const int tid  = threadIdx.x;
    const int lane = tid & 63;
    const int w    = tid >> 6;                 // wave 0..3
    const int half = blockIdx.x & 1;           // code half 0/1
    const int bmBase = (blockIdx.x >> 1) * 128;
    const int cbase  = half * 2048;            // global col offset

    // half-cbn -> LDS (2048 codes), 8 floats per thread
    {
        float4 c0 = *reinterpret_cast<const float4*>(&cbn[cbase + tid * 8]);
        float4 c1 = *reinterpret_cast<const float4*>(&cbn[cbase + tid * 8 + 4]);
        *reinterpret_cast<float4*>(&cbn_s[tid * 8])     = c0;
        *reinterpret_cast<float4*>(&cbn_s[tid * 8 + 4]) = c1;
    }

    // A fragments: af[mi][kq], rows bmBase + w*32 + mi*16 + (lane&15)
    bf16x8 af[2][8];
    #pragma unroll
    for (int mi = 0; mi < 2; ++mi) {
        int arow = bmBase + w * 32 + mi * 16 + (lane & 15);
        const short* ap = Xh + ((size_t)arow << 8) + (lane >> 4) * 8;
        #pragma unroll
        for (int kq = 0; kq < 8; ++kq)
            af[mi][kq] = *reinterpret_cast<const bf16x8*>(ap + kq * 32);
    }
    float xxv[2][4], dlt[2][4], rmin[2][4];
    const float cmax = __uint_as_float(*cbn_max);
    #pragma unroll
    for (int mi = 0; mi < 2; ++mi)
        #pragma unroll
        for (int rg = 0; rg < 4; ++rg) {
            xxv[mi][rg] = xx[bmBase + w * 32 + mi * 16 + (lane >> 4) * 4 + rg];
            dlt[mi][rg] = fmaf(0.003f, sqrtf(xxv[mi][rg] * cmax), 0.01f);
            rmin[mi][rg] = 1e30f;
        }
    __syncthreads();        // cbn_s visible (only barrier in the kernel)

    int ccnt = 0;
    for (int t = 0; t < 16; ++t) {             // this block's 16 bn-tiles
        const int bn = half * 16 + t;          // global 128-code tile index
        f32x4 acc[2][8];
        #pragma unroll
        for (int mi = 0; mi < 2; ++mi)
            #pragma unroll
            for (int ni = 0; ni < 8; ++ni) acc[mi][ni] = f32x4{0.f, 0.f, 0.f, 0.f};

        const short* tb = CBf + (size_t)bn * 32768 + lane * 8;  // 64 frags x 512
        #pragma unroll
        for (int kq = 0; kq < 8; ++kq) {         // kb*2+ks
            bf16x8 bfv[8];
            const short* fb = tb + kq * 4096;
            #pragma unroll
            for (int ni = 0; ni < 8; ++ni)
                bfv[ni] = *reinterpret_cast<const bf16x8*>(fb + ni * 512);
            #pragma unroll
            for (int ni = 0; ni < 8; ++ni) {
                acc[0][ni] = __builtin_amdgcn_mfma_f32_16x16x32_bf16(
                    af[0][kq], bfv[ni], acc[0][ni], 0, 0, 0);
                acc[1][ni] = __builtin_amdgcn_mfma_f32_16x16x32_bf16(
                    af[1][kq], bfv[ni], acc[1][ni], 0, 0, 0);
            }
        }

        // epilogue: per-(mi,rg); local col lc in [0,2048), global col = cbase+lc
        float cb_v[8];
        #pragma unroll
        for (int ni = 0; ni < 8; ++ni)
            cb_v[ni] = cbn_s[t * 128 + ni * 16 + (lane & 15)];
        #pragma unroll
        for (int mi = 0; mi < 2; ++mi) {
            #pragma unroll
            for (int rg = 0; rg < 4; ++rg) {
                float d2v[8], m = 1e30f;
                #pragma unroll
                for (int ni = 0; ni < 8; ++ni) {
                    d2v[ni] = fmaf(-2.f, acc[mi][ni][rg], xxv[mi][rg]) + cb_v[ni];
                    m = fminf(m, d2v[ni]);
                }
                #pragma unroll
                for (int d = 1; d < 16; d <<= 1)
                    m = fminf(m, __shfl_xor(m, d, 64));
                rmin[mi][rg] = fminf(rmin[mi][rg], m);   // running min incl. tile
                float thr = rmin[mi][rg] + dlt[mi][rg];
                #pragma unroll
                for (int ni = 0; ni < 8; ++ni) {
                    if (d2v[ni] <= thr) {
                        int gcol = cbase + t * 128 + ni * 16 + (lane & 15);
                        u32 enc = ((u32)(mi * 4 + rg) << 16) | (u32)gcol;
                        if (ccnt < 8) cand_lds[ccnt][tid] = enc;
                        else exact_rerank(X, CB, xx, cbn,   // ~never: stricter only
                                 bmBase + w * 32 + mi * 16 + (lane >> 4) * 4 + rg,
                                 gcol, best);
                        ++ccnt;
                    }
                }
            }
        }
    }

    // post-loop: exact fp32 rerank of buffered candidates (R2's tree)
    int nc = ccnt < 8 ? ccnt : 8;
    for (int i = 0; i < nc; ++i) {
        u32 e = cand_lds[i][tid];
        int em = (int)(e >> 16), mi = em >> 2, rg = em & 3;
        int row = bmBase + w * 32 + mi * 16 + (lane >> 4) * 4 + rg;
        exact_rerank(X, CB, xx, cbn, row, (int)(e & 0xFFFF), best);
    }
}

// ---------- kernel 3: gather e, Householder STE ----------
__global__ __launch_bounds__(256) void k_epilogue(const float* __restrict__ X,
                                                  const float* __restrict__ CB,
                                                  const u64* __restrict__ best,
                                                  float* __restrict__ Eout,
                                                  float* __restrict__ Sout) {
    int r    = blockIdx.x * 4 + (threadIdx.x >> 6);
    int lane = threadIdx.x & 63;
    int idx  = (int)(best[r] & 0xffffffffull);

    float4 xv = *reinterpret_cast<const float4*>(X  + (size_t)r   * COLS + lane * 4);
    float4 ev = *reinterpret_cast<const float4*>(CB + (size_t)idx * COLS + lane * 4);

    float xn2 = wave_sum(dot4(xv, xv));
    float en2 = wave_sum(dot4(ev, ev));
    float xn = sqrtf(xn2), en = sqrtf(en2);
    float invx = 1.f / fmaxf(xn, EPSF);
    float inve = 1.f / fmaxf(en, EPSF);

    float4 xd, ed, sd0;
    xd.x = xv.x*invx; xd.y = xv.y*invx; xd.z = xv.z*invx; xd.w = xv.w*invx;
    ed.x = ev.x*inve; ed.y = ev.y*inve; ed.z = ev.z*inve; ed.w = ev.w*inve;
    sd0.x = xd.x+ed.x; sd0.y = xd.y+ed.y; sd0.z = xd.z+ed.z; sd0.w = xd.w+ed.w;

    float sdn2 = wave_sum(dot4(sd0, sd0));
    float p1   = wave_sum(dot4(sd0, xv));
    float p2   = wave_sum(dot4(xd,  xv));
    float invs = 1.f / fmaxf(sqrtf(sdn2), EPSF);

    float csd = -2.f * invs * invs * p1;
    float ced =  2.f * p2;
    float4 rr;
    rr.x = fmaf(csd, sd0.x, fmaf(ced, ed.x, xv.x));
    rr.y = fmaf(csd, sd0.y, fmaf(ced, ed.y, xv.y));
    rr.z = fmaf(csd, sd0.z, fmaf(ced, ed.z, xv.z));
    rr.w = fmaf(csd, sd0.w, fmaf(ced, ed.w, xv.w));
    float sc = en * invx;
    float4 sv; sv.x = rr.x*sc; sv.y = rr.y*sc; sv.z = rr.z*sc; sv.w = rr.w*sc;

    *reinterpret_cast<float4*>(Eout + (size_t)r * COLS + lane * 4) = ev;
    *reinterpret_cast<float4*>(Sout + (size_t)r * COLS + lane * 4) = sv;
}

// ---------- launcher ----------
extern "C" void kernel_launch(void* const* d_in, const int* in_sizes, int n_in,
                              void* d_out, int out_size, void* d_ws, size_t ws_size,
                              hipStream_t stream) {
    const float* x  = (const float*)d_in[0];
    const float* fc = (const float*)d_in[1];
    const float* Wi = (const float*)d_in[2];
    const float* Wo = (const float*)d_in[3];

    // ws layout (~5 MB)
    char* ws = (char*)d_ws;
    u64*   best    = (u64*)ws;                            ws += (size_t)ROWS * 8;
    float* CBws    = (float*)ws;                          ws += (size_t)Nn * COLS * 4;
    float* cbn     = (float*)ws;                          ws += (size_t)Nn * 4;
    float* xx      = (float*)ws;                          ws += (size_t)ROWS * 4;
    u32*   cbn_max = (u32*)ws;

    // bf16 copies live in d_out (128 MiB), only overwritten by k_epilogue at
    // the very end: Xh = 32 MiB at offset 0, CBf = 2 MiB at offset 64 MiB.
    short* Xh  = (short*)d_out;
    short* CBf = (short*)((char*)d_out + (64u << 20));

    float* Eout = (float*)d_out;
    float* Sout = Eout + (size_t)ROWS * COLS;

    k_prep<<<ROWS / 4, 256, 0, stream>>>(x, Xh, xx, best, cbn_max);
    k_codebook<<<Nn, 256, 0, stream>>>(fc, Wi, Wo, CBws, CBf, cbn, cbn_max);
    k_screen_fused<<<(ROWS / 128) * 2, 256, 0, stream>>>(Xh, CBf, x, CBws, cbn, xx, best, cbn_max);
    k_epilogue<<<ROWS / 4, 256, 0, stream>>>(x, CBws, best, Eout, Sout);
}

// Round 12
// 407.119 us; speedup vs baseline: 1.8326x; 1.4249x over previous
//
#include <hip/hip_runtime.h>
#include <hip/hip_bf16.h>
#include <stdint.h>

// Problem dims (fixed by reference)
#define Bq    8192
#define Hh    8
#define Dd    16
#define Kk    16
#define Nn    4096
#define DFf   16
#define ROWS  (Bq*Hh)          // 65536
#define COLS  (Dd*Kk)          // 256
#define EPSF  1e-6f

typedef unsigned long long u64;
typedef unsigned int u32;
typedef __attribute__((ext_vector_type(8)))  short bf16x8;
typedef __attribute__((ext_vector_type(16))) float f32x16;

// async global->LDS, 16B per lane; LDS dest = wave-uniform base + lane*16
#define GLOAD_LDS(g, l) __builtin_amdgcn_global_load_lds( \
    (const __attribute__((address_space(1))) u32*)(g), \
    (__attribute__((address_space(3))) u32*)(l), 16, 0, 0)

// ---------- helpers ----------
__device__ __forceinline__ float dot4(float4 a, float4 b) {
    return fmaf(a.x, b.x, fmaf(a.y, b.y, fmaf(a.z, b.z, a.w * b.w)));
}
__device__ __forceinline__ float wave_sum(float v) {
    #pragma unroll
    for (int m = 32; m > 0; m >>= 1) v += __shfl_xor(v, m, 64);
    return v;
}
__device__ __forceinline__ u32 f32_sortable(float f) {
    u32 u = __float_as_uint(f);
    return (u & 0x80000000u) ? ~u : (u | 0x80000000u);
}
// pack 2 floats -> 2 bf16 (RNE); low 16 bits = a
__device__ __forceinline__ u32 pk2(float a, float b) {
    union { __hip_bfloat162 h; u32 u; } v;
    v.h = __float22bfloat162_rn(make_float2(a, b));
    return v.u;
}
// exact fp32 rerank, R2's accepted expression tree (sequential fmaf over 64 float4s)
__device__ __forceinline__ void exact_rerank(const float* __restrict__ X,
                                             const float* __restrict__ CB,
                                             const float* __restrict__ xx,
                                             const float* __restrict__ cbn,
                                             int row, int col,
                                             u64* __restrict__ best) {
    const float4* xp = (const float4*)(X + (size_t)row * COLS);
    const float4* cp = (const float4*)(CB + (size_t)col * COLS);
    float d = 0.f;
    #pragma unroll 8
    for (int q = 0; q < 64; ++q) {
        float4 a = xp[q], b = cp[q];
        d = fmaf(a.x, b.x, d); d = fmaf(a.y, b.y, d);
        d = fmaf(a.z, b.z, d); d = fmaf(a.w, b.w, d);
    }
    float d2e = fmaf(-2.f, d, xx[row]) + cbn[col];
    u64 pk = ((u64)f32_sortable(d2e) << 32) | (u32)col;
    atomicMin(&best[row], pk);
}

// ---------- kernel 0: xx[r], X->bf16 (row-major), init best/cbn_max ----------
__global__ __launch_bounds__(256) void k_prep(const float* __restrict__ X,
                                              short* __restrict__ Xh,
                                              float* __restrict__ xx,
                                              u64* __restrict__ best,
                                              u32* __restrict__ cbn_max) {
    int r    = blockIdx.x * 4 + (threadIdx.x >> 6);
    int lane = threadIdx.x & 63;
    float4 v = *reinterpret_cast<const float4*>(X + (size_t)r * COLS + lane * 4);
    uint2 p; p.x = pk2(v.x, v.y); p.y = pk2(v.z, v.w);
    *reinterpret_cast<uint2*>(Xh + (size_t)r * COLS + lane * 4) = p;
    float s = wave_sum(v.x*v.x + v.y*v.y + v.z*v.z + v.w*v.w);
    if (lane == 0) { xx[r] = s; best[r] = ~0ull; }
    if (blockIdx.x == 0 && threadIdx.x == 0) *cbn_max = 0u;
}

// ---------- kernel 1: codebook fp32 + 32x32-FRAGMENT bf16 + cbn (+acc-order copy) ----------
// CBf layout (R10, HW-verified): per 32-code tile (16 KB), frag f = kstep
// (0..15) is 1 KB: lane l = h*32 + c holds code row (tile*32 + c),
// k = kstep*16 + h*8 .. +8.  cbn_f = cbn permuted into acc order:
// cbn_f[tile*32 + h*16 + r] = cbn[tile*32 + crow(r,h)], crow = (r&3)+8*(r>>2)+4h.
__global__ __launch_bounds__(256) void k_codebook(const float* __restrict__ fc,
                                                  const float* __restrict__ Wi,
                                                  const float* __restrict__ Wo,
                                                  float* __restrict__ CB,
                                                  short* __restrict__ CBf,
                                                  float* __restrict__ cbn,
                                                  float* __restrict__ cbn_f,
                                                  u32* __restrict__ cbn_max) {
    int n = blockIdx.x, tid = threadIdx.x;
    int o = tid >> 4, k = tid & 15;
    __shared__ float fcs[256], wis[256], wos[256], hs[256], sq[256];
    __shared__ short cvs_sh[256];
    fcs[tid] = fc[(size_t)n * 256 + tid];
    wis[tid] = Wi[tid];
    wos[tid] = Wo[tid];
    __syncthreads();
    float hp = 0.f;
    #pragma unroll
    for (int i = 0; i < 16; ++i) hp = fmaf(wis[o*16 + i], fcs[i*16 + k], hp);
    hs[tid] = hp;
    __syncthreads();
    float h0 = hs[o * 16];
    float x3 = h0 * h0 * h0;
    float inner = 0.7978845608028654f * fmaf(0.044715f, x3, h0);
    float g = 0.5f * h0 * (1.f + tanhf(inner));
    float hg = hp * g;
    __syncthreads();
    hs[tid] = hg;
    __syncthreads();
    float cv = 0.f;
    #pragma unroll
    for (int i = 0; i < 16; ++i) cv = fmaf(wos[o*16 + i], hs[i*16 + k], cv);
    CB[(size_t)n * 256 + tid] = cv;
    { union { __hip_bfloat16 h; short s; } c; c.h = __float2bfloat16(cv);
      cvs_sh[tid] = c.s; }
    sq[tid] = cv * cv;
    __syncthreads();
    #pragma unroll
    for (int st = 128; st > 0; st >>= 1) {
        if (tid < st) sq[tid] += sq[tid + st];
        __syncthreads();
    }
    if (tid == 0) {
        cbn[n] = sq[0];
        atomicMax(cbn_max, __float_as_uint(sq[0]));
        int tile = n >> 5, c = n & 31;
        int h = (c >> 2) & 1, r = (c & 3) | ((c >> 3) << 2);
        cbn_f[tile * 32 + h * 16 + r] = sq[0];
    }
    // swizzled write: 32 chunks of 8 bf16 -> 32x32-fragment slots
    if (tid < 32) {
        int kc = tid;                      // 8-short chunk, k = kc*8
        int tile = n >> 5, c = n & 31;
        int kstep = kc >> 1, h = kc & 1;
        size_t off = (size_t)tile * 8192 + kstep * 512 + h * 256 + c * 8;
        *reinterpret_cast<uint4*>(CBf + off) =
            *reinterpret_cast<const uint4*>(&cvs_sh[kc * 8]);
    }
}

// ---------- kernel 2: swapped-operand 32x32 screen, LDS triple-buffer ----------
// 512 blocks x 256 threads (4 waves x 32 x-rows). mfma(code_frag, x_frag):
// D col = x-row = lane&31 -> EACH LANE OWNS ONE X-ROW; its 16 acc regs are
// 16 codes (crow(r,kh)) for that row. Epilogue per tile: 16 fma + 16 fmin
// (register-only) + ONE shfl_xor(32) + 4 broadcast ds_read_b128 of cbn_f —
// vs R10's 80 shfl (DS-pipe saturation, its failure mode). rmin and delta
// are lane-local scalars. Staging = R10's proven triple buffer:
//   s_waitcnt vmcnt(8); s_barrier; 16 ds_read_b128 + 16 MFMA + epilogue;
//   s_barrier; STAGE(t+3) into freed buffer (vmcnt never 0).
// Collection safety: rmin includes current tile -> true argmin + all exact
// ties enter; exact fp32 rerank (R2 tree) + packed atomicMin merges.
// Candidates -> LDS [8][256]; overflow reranks inline (only adds waits).
__global__ __launch_bounds__(256, 2) void k_screen_fused(
        const short* __restrict__ Xh,
        const short* __restrict__ CBf,
        const float* __restrict__ X,
        const float* __restrict__ CB,
        const float* __restrict__ cbn,
        const float* __restrict__ cbn_f,
        const float* __restrict__ xx,
        u64* __restrict__ best,
        const u32* __restrict__ cbn_max) {
    __shared__ __align__(16) short Bs[3][8192];   // 3 x 16 KB code tiles
    __shared__ float cbn_fs[Nn];                  // 16 KB, acc-order
    __shared__ u32 cand_lds[8][256];              // 8 KB

    const int tid  = threadIdx.x;
    const int lane = tid & 63;
    const int w    = tid >> 6;           // wave 0..3
    const int cl   = lane & 31;          // this lane's x-row (D col)
    const int kh   = lane >> 5;          // k-half / code-half
    const int bmBase = blockIdx.x * 128; // 32 x-rows per wave
    const int myrow  = bmBase + w * 32 + cl;

#define STAGE(t_, buf) do { \
        int _t = (t_); \
        _Pragma("unroll") \
        for (int _i = 0; _i < 4; ++_i) { \
            int _f = _i * 4 + w; \
            const short* _g = CBf + (size_t)_t * 8192 + _f * 512 + lane * 8; \
            GLOAD_LDS(_g, &Bs[(buf)][_f * 512]); \
        } \
    } while (0)

    // cbn_f -> LDS (acc-order, all 4096 codes)
    #pragma unroll
    for (int j = 0; j < 4; ++j)
        *reinterpret_cast<float4*>(&cbn_fs[tid * 16 + j * 4]) =
            *reinterpret_cast<const float4*>(&cbn_f[tid * 16 + j * 4]);

    // X fragments (B-operand): af[kstep], lane holds x-row myrow,
    // k = kstep*16 + kh*8 .. +8
    bf16x8 af[16];
    {
        const short* ap = Xh + ((size_t)myrow << 8) + kh * 8;
        #pragma unroll
        for (int ks = 0; ks < 16; ++ks)
            af[ks] = *reinterpret_cast<const bf16x8*>(ap + ks * 16);
    }

    // lane-local threshold slack (exact per-row)
    float dlt, rmin = 1e30f;
    {
        float xr = xx[myrow];
        dlt = fmaf(0.003f, sqrtf(xr * __uint_as_float(*cbn_max)), 0.01f);
    }

    __syncthreads();            // cbn_fs visible; vmcnt drained to 0 (prologue)

    STAGE(0, 0); STAGE(1, 1); STAGE(2, 2);   // 12 issues/thread outstanding

    int ccnt = 0;
    int p = 0;

    for (int t = 0; t < 128; ++t) {
        asm volatile("s_waitcnt vmcnt(8)" ::: "memory");
        __builtin_amdgcn_sched_barrier(0);
        __builtin_amdgcn_s_barrier();               // (A) buf[p] ready
        __builtin_amdgcn_sched_barrier(0);

        f32x16 acc;
        #pragma unroll
        for (int r = 0; r < 16; ++r) acc[r] = 0.f;

        const short* Bt = &Bs[p][0];
        #pragma unroll
        for (int ks = 0; ks < 16; ++ks) {
            bf16x8 cf = *reinterpret_cast<const bf16x8*>(&Bt[ks * 512 + lane * 8]);
            acc = __builtin_amdgcn_mfma_f32_32x32x16_bf16(cf, af[ks], acc, 0, 0, 0);
        }

        // epilogue: g[r] = -2*dot + cbn, codes crow(r,kh) of tile t, row = cl
        float cbnv[16];
        #pragma unroll
        for (int q = 0; q < 4; ++q)
            *reinterpret_cast<float4*>(&cbnv[q * 4]) =
                *reinterpret_cast<const float4*>(&cbn_fs[t * 32 + kh * 16 + q * 4]);
        float gv[16], m = 1e30f;
        #pragma unroll
        for (int r = 0; r < 16; ++r) {
            gv[r] = fmaf(-2.f, acc[r], cbnv[r]);
            m = fminf(m, gv[r]);
        }
        m = fminf(m, __shfl_xor(m, 32, 64));        // other code-half, same row
        rmin = fminf(rmin, m);                      // running min incl. this tile
        float thr = rmin + dlt;
        #pragma unroll
        for (int r = 0; r < 16; ++r) {
            if (gv[r] <= thr) {
                u32 code = (u32)(t * 32 + (r & 3) + 8 * (r >> 2) + 4 * kh);
                if (ccnt < 8) cand_lds[ccnt][tid] = code;
                else exact_rerank(X, CB, xx, cbn, myrow, (int)code, best);
                ++ccnt;
            }
        }

        __builtin_amdgcn_sched_barrier(0);
        __builtin_amdgcn_s_barrier();               // (B) buf[p] free
        __builtin_amdgcn_sched_barrier(0);
        STAGE((t + 3) & 127, p);    // wrap keeps vmcnt count uniform
        p = (p == 2) ? 0 : p + 1;
    }

    // post-loop: exact fp32 rerank of buffered candidates (R2's tree)
    int nc = ccnt < 8 ? ccnt : 8;
    for (int i = 0; i < nc; ++i)
        exact_rerank(X, CB, xx, cbn, myrow, (int)cand_lds[i][tid], best);
#undef STAGE
}

// ---------- kernel 3: gather e, Householder STE ----------
__global__ __launch_bounds__(256) void k_epilogue(const float* __restrict__ X,
                                                  const float* __restrict__ CB,
                                                  const u64* __restrict__ best,
                                                  float* __restrict__ Eout,
                                                  float* __restrict__ Sout) {
    int r    = blockIdx.x * 4 + (threadIdx.x >> 6);
    int lane = threadIdx.x & 63;
    int idx  = (int)(best[r] & 0xffffffffull);

    float4 xv = *reinterpret_cast<const float4*>(X  + (size_t)r   * COLS + lane * 4);
    float4 ev = *reinterpret_cast<const float4*>(CB + (size_t)idx * COLS + lane * 4);

    float xn2 = wave_sum(dot4(xv, xv));
    float en2 = wave_sum(dot4(ev, ev));
    float xn = sqrtf(xn2), en = sqrtf(en2);
    float invx = 1.f / fmaxf(xn, EPSF);
    float inve = 1.f / fmaxf(en, EPSF);

    float4 xd, ed, sd0;
    xd.x = xv.x*invx; xd.y = xv.y*invx; xd.z = xv.z*invx; xd.w = xv.w*invx;
    ed.x = ev.x*inve; ed.y = ev.y*inve; ed.z = ev.z*inve; ed.w = ev.w*inve;
    sd0.x = xd.x+ed.x; sd0.y = xd.y+ed.y; sd0.z = xd.z+ed.z; sd0.w = xd.w+ed.w;

    float sdn2 = wave_sum(dot4(sd0, sd0));
    float p1   = wave_sum(dot4(sd0, xv));
    float p2   = wave_sum(dot4(xd,  xv));
    float invs = 1.f / fmaxf(sqrtf(sdn2), EPSF);

    float csd = -2.f * invs * invs * p1;
    float ced =  2.f * p2;
    float4 rr;
    rr.x = fmaf(csd, sd0.x, fmaf(ced, ed.x, xv.x));
    rr.y = fmaf(csd, sd0.y, fmaf(ced, ed.y, xv.y));
    rr.z = fmaf(csd, sd0.z, fmaf(ced, ed.z, xv.z));
    rr.w = fmaf(csd, sd0.w, fmaf(ced, ed.w, xv.w));
    float sc = en * invx;
    float4 sv; sv.x = rr.x*sc; sv.y = rr.y*sc; sv.z = rr.z*sc; sv.w = rr.w*sc;

    *reinterpret_cast<float4*>(Eout + (size_t)r * COLS + lane * 4) = ev;
    *reinterpret_cast<float4*>(Sout + (size_t)r * COLS + lane * 4) = sv;
}

// ---------- launcher ----------
extern "C" void kernel_launch(void* const* d_in, const int* in_sizes, int n_in,
                              void* d_out, int out_size, void* d_ws, size_t ws_size,
                              hipStream_t stream) {
    const float* x  = (const float*)d_in[0];
    const float* fc = (const float*)d_in[1];
    const float* Wi = (const float*)d_in[2];
    const float* Wo = (const float*)d_in[3];

    // ws layout (~5 MB)
    char* ws = (char*)d_ws;
    u64*   best    = (u64*)ws;                            ws += (size_t)ROWS * 8;
    float* CBws    = (float*)ws;                          ws += (size_t)Nn * COLS * 4;
    float* cbn     = (float*)ws;                          ws += (size_t)Nn * 4;
    float* cbn_f   = (float*)ws;                          ws += (size_t)Nn * 4;
    float* xx      = (float*)ws;                          ws += (size_t)ROWS * 4;
    u32*   cbn_max = (u32*)ws;

    // bf16 copies live in d_out (128 MiB), only overwritten by k_epilogue at
    // the very end: Xh = 32 MiB at offset 0, CBf = 2 MiB at offset 64 MiB.
    short* Xh  = (short*)d_out;
    short* CBf = (short*)((char*)d_out + (64u << 20));

    float* Eout = (float*)d_out;
    float* Sout = Eout + (size_t)ROWS * COLS;

    k_prep<<<ROWS / 4, 256, 0, stream>>>(x, Xh, xx, best, cbn_max);
    k_codebook<<<Nn, 256, 0, stream>>>(fc, Wi, Wo, CBws, CBf, cbn, cbn_f, cbn_max);
    k_screen_fused<<<ROWS / 128, 256, 0, stream>>>(Xh, CBf, x, CBws, cbn, cbn_f, xx, best, cbn_max);
    k_epilogue<<<ROWS / 4, 256, 0, stream>>>(x, CBws, best, Eout, Sout);
}